// Round 16
// baseline (170.486 us; speedup 1.0000x reference)
//
#include <hip/hip_runtime.h>

#define NH 16
#define HS 64
#define HID 1024
#define SEQ 2048
#define BB 4
#define MR (BB*SEQ)   // 8192 rows
#define KD 1024
#define NT 32         // K-tiles of 32
#define QSCALE 0.18033688f   // 0.125 * log2(e): softmax in base-2 domain

typedef __bf16 bf16;
typedef __attribute__((ext_vector_type(8))) __bf16 bf16x8;
typedef __attribute__((ext_vector_type(4))) __bf16 bf16x4;
typedef __attribute__((ext_vector_type(4))) float f32x4;
typedef __attribute__((ext_vector_type(16))) float f32x16;
typedef __attribute__((ext_vector_type(4))) float f4;
typedef __attribute__((ext_vector_type(2))) unsigned uintx2;

typedef __attribute__((address_space(3))) unsigned int as3u;
typedef __attribute__((address_space(1))) unsigned int as1u;

__device__ __forceinline__ void gl_lds16(const void* g, void* l) {
  __builtin_amdgcn_global_load_lds((const as1u*)g, (as3u*)l, 16, 0, 0);
}

__device__ __forceinline__ f32x4 mfma16(bf16x8 a, bf16x8 b, f32x4 c) {
  return __builtin_amdgcn_mfma_f32_16x16x32_bf16(a, b, c, 0, 0, 0);
}

__device__ __forceinline__ f32x16 mfma32(bf16x8 a, bf16x8 b, f32x16 c) {
  return __builtin_amdgcn_mfma_f32_32x32x16_bf16(a, b, c, 0, 0, 0);
}

__device__ __forceinline__ uintx2 plswap(unsigned a, unsigned b) {
#if __has_builtin(__builtin_amdgcn_permlane32_swap)
  return __builtin_amdgcn_permlane32_swap(a, b, false, false);
#else
  asm volatile("v_permlane32_swap_b32 %0, %1" : "+&v"(a), "+v"(b));
  uintx2 r; r[0] = a; r[1] = b; return r;
#endif
}

__device__ __forceinline__ float xmax32(float x) {
  uintx2 r = plswap(__float_as_uint(x), __float_as_uint(x));
  return fmaxf(__uint_as_float(r[0]), __uint_as_float(r[1]));
}
__device__ __forceinline__ float xadd32(float x) {
  uintx2 r = plswap(__float_as_uint(x), __float_as_uint(x));
  return __uint_as_float(r[0]) + __uint_as_float(r[1]);
}

__device__ __forceinline__ unsigned cvtpk(float lo, float hi) {
  unsigned r;
  asm("v_cvt_pk_bf16_f32 %0, %1, %2" : "=v"(r) : "v"(lo), "v"(hi));
  return r;
}

// ---------------- fp32 -> bf16: all 5 tensors in one launch ----------------
#define XN4   (MR*HID/4)
#define WN4   (HID*KD/4)
__global__ __launch_bounds__(256) void k_cvt_all(const float* __restrict__ x,
                                                 const float* __restrict__ w0, const float* __restrict__ w1,
                                                 const float* __restrict__ w2, const float* __restrict__ w3,
                                                 bf16* __restrict__ xb,
                                                 bf16* __restrict__ o0, bf16* __restrict__ o1,
                                                 bf16* __restrict__ o2, bf16* __restrict__ o3) {
  int i = blockIdx.x * 256 + threadIdx.x;
  const float* in; bf16* out; int j;
  if (i < XN4)            { in = x;  out = xb; j = i; }
  else if (i < XN4+WN4)   { in = w0; out = o0; j = i - XN4; }
  else if (i < XN4+2*WN4) { in = w1; out = o1; j = i - XN4 - WN4; }
  else if (i < XN4+3*WN4) { in = w2; out = o2; j = i - XN4 - 2*WN4; }
  else                    { in = w3; out = o3; j = i - XN4 - 3*WN4; }
  f4 v = reinterpret_cast<const f4*>(in)[j];
  bf16x4 h;
  h[0] = (bf16)v[0]; h[1] = (bf16)v[1]; h[2] = (bf16)v[2]; h[3] = (bf16)v[3];
  reinterpret_cast<bf16x4*>(out)[j] = h;
}

// ---------------- pipelined NT GEMM (R7-proven): BM=128, BN=256, BK=32, 3-buffer, counted vmcnt ----------------
// MODE 0: QKV fused — blockIdx.y: y>>2 selects {Q,K,V}, (y&3)*256 = n0.
// MODE 1: O-projection — f32 flat out, blockIdx.y*256 = n0.
template<int MODE>
__global__ __launch_bounds__(512, 4) void k_gemm_p(const bf16* __restrict__ A,
                                                   const bf16* __restrict__ w0, const bf16* __restrict__ w1,
                                                   const bf16* __restrict__ w2,
                                                   const float* __restrict__ b0, const float* __restrict__ b1,
                                                   const float* __restrict__ b2p,
                                                   void* __restrict__ o0, void* __restrict__ o1,
                                                   void* __restrict__ o2) {
  __shared__ __align__(16) bf16 As[3][128*32];
  __shared__ __align__(16) bf16 Bs[3][256*32];
  const int tid = threadIdx.x, l = tid & 63, w = tid >> 6;
  const int wr = w >> 2, wc = w & 3;
  const int m0 = blockIdx.x * 128;
  const int ny = blockIdx.y;
  const int which = (MODE == 0) ? (ny >> 2) : 0;
  const int n0 = (MODE == 0) ? (ny & 3) * 256 : ny * 256;
  const bf16* Bw = (MODE == 1) ? w0 : (which == 0 ? w0 : which == 1 ? w1 : w2);
  const float* bias = (MODE == 1) ? b0 : (which == 0 ? b0 : which == 1 ? b1 : b2p);

  const int sra = tid >> 2;
  const int sca = (tid & 3) ^ ((sra >> 1) & 3);
  const bf16* Ag = A  + (size_t)(m0 + sra) * KD + sca * 8;
  const bf16* Bg = Bw + (size_t)(n0 + sra) * KD + sca * 8;

  gl_lds16(Ag,                        (char*)As[0] + w * 1024);
  gl_lds16(Bg,                        (char*)Bs[0] + w * 1024);
  gl_lds16(Bg + (size_t)128 * KD,     (char*)Bs[0] + 8192 + w * 1024);
  gl_lds16(Ag + 32,                   (char*)As[1] + w * 1024);
  gl_lds16(Bg + 32,                   (char*)Bs[1] + w * 1024);
  gl_lds16(Bg + (size_t)128 * KD + 32, (char*)Bs[1] + 8192 + w * 1024);

  f32x4 acc[4][4] = {};
  const int la = l & 15, lg = l >> 4;

  for (int t = 0; t < NT; ++t) {
    const int bq = t % 3;
    if (t < NT - 1) { asm volatile("s_waitcnt vmcnt(3)" ::: "memory"); }
    else            { asm volatile("s_waitcnt vmcnt(0)" ::: "memory"); }
    __builtin_amdgcn_sched_barrier(0);
    __builtin_amdgcn_s_barrier();
    __builtin_amdgcn_sched_barrier(0);

    bf16x8 af[4], bf_[2];
    #pragma unroll
    for (int mf = 0; mf < 4; mf++) {
      const int ra = wr * 64 + mf * 16 + la;
      const int ca = lg ^ ((ra >> 1) & 3);
      af[mf] = *(const bf16x8*)((const char*)As[bq] + ra * 64 + ca * 16);
    }
    #pragma unroll
    for (int nf = 0; nf < 2; nf++) {
      const int rb = wc * 64 + nf * 16 + la;
      const int cb = lg ^ ((rb >> 1) & 3);
      bf_[nf] = *(const bf16x8*)((const char*)Bs[bq] + rb * 64 + cb * 16);
    }
    const int t2 = t + 2;
    if (t2 < NT) {
      const int b2 = t2 % 3;
      gl_lds16(Ag + t2 * 32, (char*)As[b2] + w * 1024);
      gl_lds16(Bg + t2 * 32, (char*)Bs[b2] + w * 1024);
    }
    asm volatile("s_waitcnt lgkmcnt(0)" ::: "memory");
    __builtin_amdgcn_sched_barrier(0);
    __builtin_amdgcn_s_setprio(1);
    #pragma unroll
    for (int mf = 0; mf < 4; mf++) {
      acc[mf][0] = mfma16(af[mf], bf_[0], acc[mf][0]);
      acc[mf][1] = mfma16(af[mf], bf_[1], acc[mf][1]);
    }
    __builtin_amdgcn_s_setprio(0);

    #pragma unroll
    for (int nf = 0; nf < 2; nf++) {
      const int rb = wc * 64 + (nf + 2) * 16 + la;
      const int cb = lg ^ ((rb >> 1) & 3);
      bf_[nf] = *(const bf16x8*)((const char*)Bs[bq] + rb * 64 + cb * 16);
    }
    if (t2 < NT) {
      const int b2 = t2 % 3;
      gl_lds16(Bg + (size_t)128 * KD + t2 * 32, (char*)Bs[b2] + 8192 + w * 1024);
    }
    asm volatile("s_waitcnt lgkmcnt(0)" ::: "memory");
    __builtin_amdgcn_sched_barrier(0);
    __builtin_amdgcn_s_setprio(1);
    #pragma unroll
    for (int mf = 0; mf < 4; mf++) {
      acc[mf][2] = mfma16(af[mf], bf_[0], acc[mf][2]);
      acc[mf][3] = mfma16(af[mf], bf_[1], acc[mf][3]);
    }
    __builtin_amdgcn_s_setprio(0);
  }

  const float scale = (MODE == 0 && which == 0) ? QSCALE : 1.0f;
  #pragma unroll
  for (int mf = 0; mf < 4; mf++) {
    #pragma unroll
    for (int nf = 0; nf < 4; nf++) {
      const int n = n0 + wc * 64 + nf * 16 + la;
      const float bn = bias[n];
      #pragma unroll
      for (int j = 0; j < 4; j++) {
        const int m = m0 + wr * 64 + mf * 16 + lg * 4 + j;
        const float v = (acc[mf][nf][j] + bn) * scale;
        if (MODE == 0) {
          if (which == 2) {
            ((bf16*)o2)[(((size_t)(m >> 11) * NH + (n >> 6)) * HS + (n & 63)) * SEQ + (m & (SEQ - 1))] = (bf16)v;
          } else {
            bf16* dst = (which == 0) ? (bf16*)o0 : (bf16*)o1;
            dst[(((size_t)(m >> 11) * NH + (n >> 6)) * SEQ + (m & (SEQ - 1))) * HS + (n & 63)] = (bf16)v;
          }
        } else {
          ((float*)o0)[(size_t)m * HID + n] = v;
        }
      }
    }
  }
}

// ---------------- causal flash attention: Q in regs, 48KB LDS -> 3 blocks/CU, XCD-grouped grid ----------------
__global__ __launch_bounds__(256, 3) void k_attn(const bf16* __restrict__ Q,
                                                 const bf16* __restrict__ K,
                                                 const bf16* __restrict__ Vt,
                                                 bf16* __restrict__ Aout) {
  const int bh = blockIdx.x;
  const int bx = blockIdx.y;
  const int tid = threadIdx.x, l = tid & 63, w = tid >> 6;
  const int hi = l >> 5;

  __shared__ __align__(16) bf16 Ks[3][64*64];
  __shared__ __align__(16) bf16 Vs[3][64*64];

  const bf16* Qg = Q  + (size_t)bh * SEQ * HS;
  const bf16* Kg = K  + (size_t)bh * SEQ * HS;
  const bf16* Vg = Vt + (size_t)bh * HS * SEQ;   // [d][s]

  const int bb = bh >> 4, hh = bh & 15;
  const int sr  = tid >> 3;
  const int swz = ((tid & 7) ^ (sr & 7)) * 8;

  for (int pass = 0; pass < 2; ++pass) {
    const int p_ = pass ? (15 - bx) : bx;
    const int q0 = p_ * 128;
    const int nt = 2 * p_ + 2;

    bf16x8 qf[4];
    {
      const bf16* qrow = Qg + (size_t)(q0 + w*32 + (l & 31)) * HS + hi * 8;
      #pragma unroll
      for (int m = 0; m < 4; m++)
        qf[m] = *(const bf16x8*)(qrow + m * 16);
    }
    __builtin_amdgcn_sched_barrier(0);

    #pragma unroll
    for (int i = 0; i < 2; i++) {
      gl_lds16(Kg + (size_t)(32*i + sr) * HS + swz,  (char*)Ks[0] + i*4096 + w*1024);
      gl_lds16(Vg + (size_t)(32*i + sr) * SEQ + swz, (char*)Vs[0] + i*4096 + w*1024);
    }
    #pragma unroll
    for (int i = 0; i < 2; i++) {
      gl_lds16(Kg + (size_t)(64 + 32*i + sr) * HS + swz,  (char*)Ks[1] + i*4096 + w*1024);
      gl_lds16(Vg + (size_t)(32*i + sr) * SEQ + 64 + swz, (char*)Vs[1] + i*4096 + w*1024);
    }
    asm volatile("s_waitcnt vmcnt(4)" ::: "memory");
    __builtin_amdgcn_sched_barrier(0);
    __builtin_amdgcn_s_barrier();
    __builtin_amdgcn_sched_barrier(0);

    float m_r = -1e30f, l_r = 0.f;
    f32x16 o[2] = {};
    const int qmax = q0 + w*32 + 31;
    const int qg   = q0 + w*32 + (l & 31);

    int cur = 0;
    for (int kt = 0; kt < nt; ++kt) {
      const int k0 = kt * 64;

      if (kt + 2 < nt) {
        const int k2 = k0 + 128;
        const int b2 = (cur == 0) ? 2 : cur - 1;
        #pragma unroll
        for (int i = 0; i < 2; i++) {
          gl_lds16(Kg + (size_t)(k2 + 32*i + sr) * HS + swz,  (char*)Ks[b2] + i*4096 + w*1024);
          gl_lds16(Vg + (size_t)(32*i + sr) * SEQ + k2 + swz, (char*)Vs[b2] + i*4096 + w*1024);
        }
      }

      if (k0 <= qmax) {
        f32x16 p[2] = {};
        #pragma unroll
        for (int b = 0; b < 2; b++) {
          #pragma unroll
          for (int m = 0; m < 4; m++) {
            const int row = 32*b + (l & 31);
            const int cc = 2*m + hi;
            bf16x8 kf = *(const bf16x8*)((const char*)Ks[cur] + row*128 + ((cc ^ (row & 7))*16));
            p[b] = mfma32(kf, qf[m], p[b]);
          }
        }

        if (k0 + 63 > q0 + w*32) {
          #pragma unroll
          for (int b = 0; b < 2; b++)
            #pragma unroll
            for (int r = 0; r < 16; r++) {
              const int kg = k0 + 32*b + (r & 3) + 8*(r >> 2) + 4*hi;
              if (kg > qg) p[b][r] = -1e30f;
            }
        }

        float rloc = -1e30f;
        #pragma unroll
        for (int b = 0; b < 2; b++)
          #pragma unroll
          for (int r = 0; r < 16; r++) rloc = fmaxf(rloc, p[b][r]);
        const float rmax = xmax32(rloc);

        if (__any(rmax > m_r + 8.0f)) {
          const float mn = fmaxf(m_r, rmax);
          const float alpha = __builtin_amdgcn_exp2f(m_r - mn);
          m_r = mn;
          l_r *= alpha;
          #pragma unroll
          for (int r = 0; r < 16; r++) {
            const float ar = __shfl(alpha, (r & 3) + 8*(r >> 2) + 4*hi);
            o[0][r] *= ar; o[1][r] *= ar;
          }
        }

        float sloc = 0.f;
        #pragma unroll
        for (int b = 0; b < 2; b++)
          #pragma unroll
          for (int r = 0; r < 16; r++) {
            const float e = __builtin_amdgcn_exp2f(p[b][r] - m_r);
            p[b][r] = e;
            sloc += e;
          }
        l_r += xadd32(sloc);

        bf16x8 pa[4];
        #pragma unroll
        for (int c = 0; c < 4; c++) {
          const int b = c >> 1, R = (c & 1) * 8;
          unsigned w01 = cvtpk(p[b][R+0], p[b][R+1]);
          unsigned w23 = cvtpk(p[b][R+2], p[b][R+3]);
          unsigned w89 = cvtpk(p[b][R+4], p[b][R+5]);
          unsigned wab = cvtpk(p[b][R+6], p[b][R+7]);
          uintx2 s1 = plswap(w01, w89);
          uintx2 s2 = plswap(w23, wab);
          union { unsigned u[4]; bf16x8 v; } uu;
          uu.u[0] = s1[0]; uu.u[1] = s2[0]; uu.u[2] = s1[1]; uu.u[3] = s2[1];
          pa[c] = uu.v;
        }

        #pragma unroll
        for (int d = 0; d < 2; d++) {
          #pragma unroll
          for (int c = 0; c < 4; c++) {
            const int row = 32*d + (l & 31);
            const int cc = 2*c + hi;
            bf16x8 vf = *(const bf16x8*)((const char*)Vs[cur] + row*128 + ((cc ^ (row & 7))*16));
            o[d] = mfma32(pa[c], vf, o[d]);
          }
        }
      }

      if (kt + 2 < nt) { asm volatile("s_waitcnt vmcnt(4)" ::: "memory"); }
      else             { asm volatile("s_waitcnt vmcnt(0)" ::: "memory"); }
      __builtin_amdgcn_sched_barrier(0);
      __builtin_amdgcn_s_barrier();
      __builtin_amdgcn_sched_barrier(0);
      cur = (cur == 2) ? 0 : cur + 1;
    }

    const float inv = 1.0f / l_r;
    #pragma unroll
    for (int r = 0; r < 16; r++) {
      const int qr = (r & 3) + 8*(r >> 2) + 4*hi;
      const float ir = __shfl(inv, qr);
      const int q = q0 + w*32 + qr;
      #pragma unroll
      for (int d = 0; d < 2; d++)
        Aout[(size_t)(bb*SEQ + q)*HID + hh*HS + d*32 + (l & 31)] = (bf16)(o[d][r] * ir);
    }
  }
}

// ---------------- launch ----------------
extern "C" void kernel_launch(void* const* d_in, const int* in_sizes, int n_in,
                              void* d_out, int out_size, void* d_ws, size_t ws_size,
                              hipStream_t stream) {
  const float* x  = (const float*)d_in[0];
  const float* Wq = (const float*)d_in[1];
  const float* bq = (const float*)d_in[2];
  const float* Wk = (const float*)d_in[3];
  const float* bk = (const float*)d_in[4];
  const float* Wv = (const float*)d_in[5];
  const float* bv = (const float*)d_in[6];
  const float* Wo = (const float*)d_in[7];
  const float* bo = (const float*)d_in[8];

  char* ws = (char*)d_ws;
  const size_t MB = 1024 * 1024;
  bf16* xb  = (bf16*)(ws);
  bf16* wqb = (bf16*)(ws + 16*MB);
  bf16* wkb = (bf16*)(ws + 18*MB);
  bf16* wvb = (bf16*)(ws + 20*MB);
  bf16* wob = (bf16*)(ws + 22*MB);
  bf16* Qb  = (bf16*)(ws + 24*MB);
  bf16* Kb  = (bf16*)(ws + 40*MB);
  bf16* Vb  = (bf16*)(ws + 56*MB);
  bf16* Ab  = xb;

  k_cvt_all<<<(XN4 + 4*WN4 + 255)/256, 256, 0, stream>>>(x, Wq, Wk, Wv, Wo, xb, wqb, wkb, wvb, wob);

  k_gemm_p<0><<<dim3(MR/128, 12), 512, 0, stream>>>(xb, wqb, wkb, wvb, bq, bk, bv, Qb, Kb, Vb);

  k_attn<<<dim3(BB*NH, 8), 256, 0, stream>>>(Qb, Kb, Vb, Ab);

  k_gemm_p<1><<<dim3(MR/128, 4), 512, 0, stream>>>(Ab, wob, wob, wob, bo, bo, bo, d_out, d_out, d_out);
}

// Round 17
// 168.307 us; speedup vs baseline: 1.0129x; 1.0129x over previous
//
#include <hip/hip_runtime.h>

#define NH 16
#define HS 64
#define HID 1024
#define SEQ 2048
#define BB 4
#define MR (BB*SEQ)   // 8192 rows
#define KD 1024
#define NT 32         // K-tiles of 32
#define QSCALE 0.18033688f   // 0.125 * log2(e): softmax in base-2 domain

typedef __bf16 bf16;
typedef __attribute__((ext_vector_type(8))) __bf16 bf16x8;
typedef __attribute__((ext_vector_type(4))) __bf16 bf16x4;
typedef __attribute__((ext_vector_type(4))) float f32x4;
typedef __attribute__((ext_vector_type(16))) float f32x16;
typedef __attribute__((ext_vector_type(4))) float f4;
typedef __attribute__((ext_vector_type(2))) unsigned uintx2;

typedef __attribute__((address_space(3))) unsigned int as3u;
typedef __attribute__((address_space(1))) unsigned int as1u;

__device__ __forceinline__ void gl_lds16(const void* g, void* l) {
  __builtin_amdgcn_global_load_lds((const as1u*)g, (as3u*)l, 16, 0, 0);
}

__device__ __forceinline__ f32x4 mfma16(bf16x8 a, bf16x8 b, f32x4 c) {
  return __builtin_amdgcn_mfma_f32_16x16x32_bf16(a, b, c, 0, 0, 0);
}

__device__ __forceinline__ f32x16 mfma32(bf16x8 a, bf16x8 b, f32x16 c) {
  return __builtin_amdgcn_mfma_f32_32x32x16_bf16(a, b, c, 0, 0, 0);
}

__device__ __forceinline__ uintx2 plswap(unsigned a, unsigned b) {
#if __has_builtin(__builtin_amdgcn_permlane32_swap)
  return __builtin_amdgcn_permlane32_swap(a, b, false, false);
#else
  asm volatile("v_permlane32_swap_b32 %0, %1" : "+&v"(a), "+v"(b));
  uintx2 r; r[0] = a; r[1] = b; return r;
#endif
}

__device__ __forceinline__ float xmax32(float x) {
  uintx2 r = plswap(__float_as_uint(x), __float_as_uint(x));
  return fmaxf(__uint_as_float(r[0]), __uint_as_float(r[1]));
}
__device__ __forceinline__ float xadd32(float x) {
  uintx2 r = plswap(__float_as_uint(x), __float_as_uint(x));
  return __uint_as_float(r[0]) + __uint_as_float(r[1]);
}

__device__ __forceinline__ unsigned cvtpk(float lo, float hi) {
  unsigned r;
  asm("v_cvt_pk_bf16_f32 %0, %1, %2" : "=v"(r) : "v"(lo), "v"(hi));
  return r;
}

// ---------------- fp32 -> bf16: all 5 tensors in one launch ----------------
#define XN4   (MR*HID/4)
#define WN4   (HID*KD/4)
__global__ __launch_bounds__(256) void k_cvt_all(const float* __restrict__ x,
                                                 const float* __restrict__ w0, const float* __restrict__ w1,
                                                 const float* __restrict__ w2, const float* __restrict__ w3,
                                                 bf16* __restrict__ xb,
                                                 bf16* __restrict__ o0, bf16* __restrict__ o1,
                                                 bf16* __restrict__ o2, bf16* __restrict__ o3) {
  int i = blockIdx.x * 256 + threadIdx.x;
  const float* in; bf16* out; int j;
  if (i < XN4)            { in = x;  out = xb; j = i; }
  else if (i < XN4+WN4)   { in = w0; out = o0; j = i - XN4; }
  else if (i < XN4+2*WN4) { in = w1; out = o1; j = i - XN4 - WN4; }
  else if (i < XN4+3*WN4) { in = w2; out = o2; j = i - XN4 - 2*WN4; }
  else                    { in = w3; out = o3; j = i - XN4 - 3*WN4; }
  f4 v = reinterpret_cast<const f4*>(in)[j];
  bf16x4 h;
  h[0] = (bf16)v[0]; h[1] = (bf16)v[1]; h[2] = (bf16)v[2]; h[3] = (bf16)v[3];
  reinterpret_cast<bf16x4*>(out)[j] = h;
}

// ---------------- pipelined NT GEMM (R7-proven): BM=128, BN=256, BK=32, 3-buffer, counted vmcnt ----------------
// MODE 0: QKV fused — blockIdx.y: y>>2 selects {Q,K,V}, (y&3)*256 = n0.
template<int MODE>
__global__ __launch_bounds__(512, 4) void k_gemm_p(const bf16* __restrict__ A,
                                                   const bf16* __restrict__ w0, const bf16* __restrict__ w1,
                                                   const bf16* __restrict__ w2,
                                                   const float* __restrict__ b0, const float* __restrict__ b1,
                                                   const float* __restrict__ b2p,
                                                   void* __restrict__ o0, void* __restrict__ o1,
                                                   void* __restrict__ o2) {
  __shared__ __align__(16) bf16 As[3][128*32];
  __shared__ __align__(16) bf16 Bs[3][256*32];
  const int tid = threadIdx.x, l = tid & 63, w = tid >> 6;
  const int wr = w >> 2, wc = w & 3;
  const int m0 = blockIdx.x * 128;
  const int ny = blockIdx.y;
  const int which = (MODE == 0) ? (ny >> 2) : 0;
  const int n0 = (MODE == 0) ? (ny & 3) * 256 : ny * 256;
  const bf16* Bw = (MODE == 1) ? w0 : (which == 0 ? w0 : which == 1 ? w1 : w2);
  const float* bias = (MODE == 1) ? b0 : (which == 0 ? b0 : which == 1 ? b1 : b2p);

  const int sra = tid >> 2;
  const int sca = (tid & 3) ^ ((sra >> 1) & 3);
  const bf16* Ag = A  + (size_t)(m0 + sra) * KD + sca * 8;
  const bf16* Bg = Bw + (size_t)(n0 + sra) * KD + sca * 8;

  gl_lds16(Ag,                        (char*)As[0] + w * 1024);
  gl_lds16(Bg,                        (char*)Bs[0] + w * 1024);
  gl_lds16(Bg + (size_t)128 * KD,     (char*)Bs[0] + 8192 + w * 1024);
  gl_lds16(Ag + 32,                   (char*)As[1] + w * 1024);
  gl_lds16(Bg + 32,                   (char*)Bs[1] + w * 1024);
  gl_lds16(Bg + (size_t)128 * KD + 32, (char*)Bs[1] + 8192 + w * 1024);

  f32x4 acc[4][4] = {};
  const int la = l & 15, lg = l >> 4;

  for (int t = 0; t < NT; ++t) {
    const int bq = t % 3;
    if (t < NT - 1) { asm volatile("s_waitcnt vmcnt(3)" ::: "memory"); }
    else            { asm volatile("s_waitcnt vmcnt(0)" ::: "memory"); }
    __builtin_amdgcn_sched_barrier(0);
    __builtin_amdgcn_s_barrier();
    __builtin_amdgcn_sched_barrier(0);

    bf16x8 af[4], bf_[2];
    #pragma unroll
    for (int mf = 0; mf < 4; mf++) {
      const int ra = wr * 64 + mf * 16 + la;
      const int ca = lg ^ ((ra >> 1) & 3);
      af[mf] = *(const bf16x8*)((const char*)As[bq] + ra * 64 + ca * 16);
    }
    #pragma unroll
    for (int nf = 0; nf < 2; nf++) {
      const int rb = wc * 64 + nf * 16 + la;
      const int cb = lg ^ ((rb >> 1) & 3);
      bf_[nf] = *(const bf16x8*)((const char*)Bs[bq] + rb * 64 + cb * 16);
    }
    const int t2 = t + 2;
    if (t2 < NT) {
      const int b2 = t2 % 3;
      gl_lds16(Ag + t2 * 32, (char*)As[b2] + w * 1024);
      gl_lds16(Bg + t2 * 32, (char*)Bs[b2] + w * 1024);
    }
    asm volatile("s_waitcnt lgkmcnt(0)" ::: "memory");
    __builtin_amdgcn_sched_barrier(0);
    __builtin_amdgcn_s_setprio(1);
    #pragma unroll
    for (int mf = 0; mf < 4; mf++) {
      acc[mf][0] = mfma16(af[mf], bf_[0], acc[mf][0]);
      acc[mf][1] = mfma16(af[mf], bf_[1], acc[mf][1]);
    }
    __builtin_amdgcn_s_setprio(0);

    #pragma unroll
    for (int nf = 0; nf < 2; nf++) {
      const int rb = wc * 64 + (nf + 2) * 16 + la;
      const int cb = lg ^ ((rb >> 1) & 3);
      bf_[nf] = *(const bf16x8*)((const char*)Bs[bq] + rb * 64 + cb * 16);
    }
    if (t2 < NT) {
      const int b2 = t2 % 3;
      gl_lds16(Bg + (size_t)128 * KD + t2 * 32, (char*)Bs[b2] + 8192 + w * 1024);
    }
    asm volatile("s_waitcnt lgkmcnt(0)" ::: "memory");
    __builtin_amdgcn_sched_barrier(0);
    __builtin_amdgcn_s_setprio(1);
    #pragma unroll
    for (int mf = 0; mf < 4; mf++) {
      acc[mf][2] = mfma16(af[mf], bf_[0], acc[mf][2]);
      acc[mf][3] = mfma16(af[mf], bf_[1], acc[mf][3]);
    }
    __builtin_amdgcn_s_setprio(0);
  }

  const float scale = (MODE == 0 && which == 0) ? QSCALE : 1.0f;
  #pragma unroll
  for (int mf = 0; mf < 4; mf++) {
    #pragma unroll
    for (int nf = 0; nf < 4; nf++) {
      const int n = n0 + wc * 64 + nf * 16 + la;
      const float bn = bias[n];
      #pragma unroll
      for (int j = 0; j < 4; j++) {
        const int m = m0 + wr * 64 + mf * 16 + lg * 4 + j;
        const float v = (acc[mf][nf][j] + bn) * scale;
        if (MODE == 0) {
          if (which == 2) {
            ((bf16*)o2)[(((size_t)(m >> 11) * NH + (n >> 6)) * HS + (n & 63)) * SEQ + (m & (SEQ - 1))] = (bf16)v;
          } else {
            bf16* dst = (which == 0) ? (bf16*)o0 : (bf16*)o1;
            dst[(((size_t)(m >> 11) * NH + (n >> 6)) * SEQ + (m & (SEQ - 1))) * HS + (n & 63)] = (bf16)v;
          }
        } else {
          ((float*)o0)[(size_t)m * HID + n] = v;
        }
      }
    }
  }
}

// ---------------- o-proj GEMM: BM=128, BN=128, 256 thr, 3-buf, 48KB -> 3/CU, 512 blocks ----------------
__global__ __launch_bounds__(256, 3) void k_gemm_o(const bf16* __restrict__ A,
                                                   const bf16* __restrict__ Bw,
                                                   const float* __restrict__ bias,
                                                   float* __restrict__ outp) {
  __shared__ __align__(16) bf16 As[3][128*32];
  __shared__ __align__(16) bf16 Bs[3][128*32];
  const int tid = threadIdx.x, l = tid & 63, w = tid >> 6;
  const int wr = w >> 1, wc = w & 1;
  const int m0 = blockIdx.x * 128;
  const int n0 = blockIdx.y * 128;

  const int sra = tid >> 2;
  const int sca = (tid & 3) ^ ((sra >> 1) & 3);
  const bf16* Ag = A  + (size_t)(m0 + sra) * KD + sca * 8;
  const bf16* Bg = Bw + (size_t)(n0 + sra) * KD + sca * 8;

  gl_lds16(Ag,                        (char*)As[0] + w * 1024);
  gl_lds16(Ag + (size_t)64 * KD,      (char*)As[0] + 4096 + w * 1024);
  gl_lds16(Bg,                        (char*)Bs[0] + w * 1024);
  gl_lds16(Bg + (size_t)64 * KD,      (char*)Bs[0] + 4096 + w * 1024);
  gl_lds16(Ag + 32,                   (char*)As[1] + w * 1024);
  gl_lds16(Ag + (size_t)64 * KD + 32, (char*)As[1] + 4096 + w * 1024);
  gl_lds16(Bg + 32,                   (char*)Bs[1] + w * 1024);
  gl_lds16(Bg + (size_t)64 * KD + 32, (char*)Bs[1] + 4096 + w * 1024);

  f32x4 acc[4][4] = {};
  const int la = l & 15, lg = l >> 4;

  for (int t = 0; t < NT; ++t) {
    const int bq = t % 3;
    if (t < NT - 1) { asm volatile("s_waitcnt vmcnt(4)" ::: "memory"); }
    else            { asm volatile("s_waitcnt vmcnt(0)" ::: "memory"); }
    __builtin_amdgcn_sched_barrier(0);
    __builtin_amdgcn_s_barrier();
    __builtin_amdgcn_sched_barrier(0);

    bf16x8 af[4], bf_[2];
    #pragma unroll
    for (int mf = 0; mf < 4; mf++) {
      const int ra = wr * 64 + mf * 16 + la;
      const int ca = lg ^ ((ra >> 1) & 3);
      af[mf] = *(const bf16x8*)((const char*)As[bq] + ra * 64 + ca * 16);
    }
    #pragma unroll
    for (int nf = 0; nf < 2; nf++) {
      const int rb = wc * 64 + nf * 16 + la;
      const int cb = lg ^ ((rb >> 1) & 3);
      bf_[nf] = *(const bf16x8*)((const char*)Bs[bq] + rb * 64 + cb * 16);
    }
    const int t2 = t + 2;
    if (t2 < NT) {
      const int b2 = t2 % 3;
      gl_lds16(Ag + t2 * 32,                   (char*)As[b2] + w * 1024);
      gl_lds16(Ag + (size_t)64 * KD + t2 * 32, (char*)As[b2] + 4096 + w * 1024);
    }
    asm volatile("s_waitcnt lgkmcnt(0)" ::: "memory");
    __builtin_amdgcn_sched_barrier(0);
    __builtin_amdgcn_s_setprio(1);
    #pragma unroll
    for (int mf = 0; mf < 4; mf++) {
      acc[mf][0] = mfma16(af[mf], bf_[0], acc[mf][0]);
      acc[mf][1] = mfma16(af[mf], bf_[1], acc[mf][1]);
    }
    __builtin_amdgcn_s_setprio(0);

    #pragma unroll
    for (int nf = 0; nf < 2; nf++) {
      const int rb = wc * 64 + (nf + 2) * 16 + la;
      const int cb = lg ^ ((rb >> 1) & 3);
      bf_[nf] = *(const bf16x8*)((const char*)Bs[bq] + rb * 64 + cb * 16);
    }
    if (t2 < NT) {
      const int b2 = t2 % 3;
      gl_lds16(Bg + t2 * 32,                   (char*)Bs[b2] + w * 1024);
      gl_lds16(Bg + (size_t)64 * KD + t2 * 32, (char*)Bs[b2] + 4096 + w * 1024);
    }
    asm volatile("s_waitcnt lgkmcnt(0)" ::: "memory");
    __builtin_amdgcn_sched_barrier(0);
    __builtin_amdgcn_s_setprio(1);
    #pragma unroll
    for (int mf = 0; mf < 4; mf++) {
      acc[mf][2] = mfma16(af[mf], bf_[0], acc[mf][2]);
      acc[mf][3] = mfma16(af[mf], bf_[1], acc[mf][3]);
    }
    __builtin_amdgcn_s_setprio(0);
  }

  #pragma unroll
  for (int mf = 0; mf < 4; mf++) {
    #pragma unroll
    for (int nf = 0; nf < 4; nf++) {
      const int n = n0 + wc * 64 + nf * 16 + la;
      const float bn = bias[n];
      #pragma unroll
      for (int j = 0; j < 4; j++) {
        const int m = m0 + wr * 64 + mf * 16 + lg * 4 + j;
        outp[(size_t)m * HID + n] = acc[mf][nf][j] + bn;
      }
    }
  }
}

// ---------------- causal flash attention: Q in regs, 48KB LDS -> 3 blocks/CU, XCD-grouped grid ----------------
__global__ __launch_bounds__(256, 3) void k_attn(const bf16* __restrict__ Q,
                                                 const bf16* __restrict__ K,
                                                 const bf16* __restrict__ Vt,
                                                 bf16* __restrict__ Aout) {
  const int bh = blockIdx.x;
  const int bx = blockIdx.y;
  const int tid = threadIdx.x, l = tid & 63, w = tid >> 6;
  const int hi = l >> 5;

  __shared__ __align__(16) bf16 Ks[3][64*64];
  __shared__ __align__(16) bf16 Vs[3][64*64];

  const bf16* Qg = Q  + (size_t)bh * SEQ * HS;
  const bf16* Kg = K  + (size_t)bh * SEQ * HS;
  const bf16* Vg = Vt + (size_t)bh * HS * SEQ;   // [d][s]

  const int bb = bh >> 4, hh = bh & 15;
  const int sr  = tid >> 3;
  const int swz = ((tid & 7) ^ (sr & 7)) * 8;

  for (int pass = 0; pass < 2; ++pass) {
    const int p_ = pass ? (15 - bx) : bx;
    const int q0 = p_ * 128;
    const int nt = 2 * p_ + 2;

    bf16x8 qf[4];
    {
      const bf16* qrow = Qg + (size_t)(q0 + w*32 + (l & 31)) * HS + hi * 8;
      #pragma unroll
      for (int m = 0; m < 4; m++)
        qf[m] = *(const bf16x8*)(qrow + m * 16);
    }
    __builtin_amdgcn_sched_barrier(0);

    #pragma unroll
    for (int i = 0; i < 2; i++) {
      gl_lds16(Kg + (size_t)(32*i + sr) * HS + swz,  (char*)Ks[0] + i*4096 + w*1024);
      gl_lds16(Vg + (size_t)(32*i + sr) * SEQ + swz, (char*)Vs[0] + i*4096 + w*1024);
    }
    #pragma unroll
    for (int i = 0; i < 2; i++) {
      gl_lds16(Kg + (size_t)(64 + 32*i + sr) * HS + swz,  (char*)Ks[1] + i*4096 + w*1024);
      gl_lds16(Vg + (size_t)(32*i + sr) * SEQ + 64 + swz, (char*)Vs[1] + i*4096 + w*1024);
    }
    asm volatile("s_waitcnt vmcnt(4)" ::: "memory");
    __builtin_amdgcn_sched_barrier(0);
    __builtin_amdgcn_s_barrier();
    __builtin_amdgcn_sched_barrier(0);

    float m_r = -1e30f, l_r = 0.f;
    f32x16 o[2] = {};
    const int qmax = q0 + w*32 + 31;
    const int qg   = q0 + w*32 + (l & 31);

    int cur = 0;
    for (int kt = 0; kt < nt; ++kt) {
      const int k0 = kt * 64;

      if (kt + 2 < nt) {
        const int k2 = k0 + 128;
        const int b2 = (cur == 0) ? 2 : cur - 1;
        #pragma unroll
        for (int i = 0; i < 2; i++) {
          gl_lds16(Kg + (size_t)(k2 + 32*i + sr) * HS + swz,  (char*)Ks[b2] + i*4096 + w*1024);
          gl_lds16(Vg + (size_t)(32*i + sr) * SEQ + k2 + swz, (char*)Vs[b2] + i*4096 + w*1024);
        }
      }

      if (k0 <= qmax) {
        f32x16 p[2] = {};
        #pragma unroll
        for (int b = 0; b < 2; b++) {
          #pragma unroll
          for (int m = 0; m < 4; m++) {
            const int row = 32*b + (l & 31);
            const int cc = 2*m + hi;
            bf16x8 kf = *(const bf16x8*)((const char*)Ks[cur] + row*128 + ((cc ^ (row & 7))*16));
            p[b] = mfma32(kf, qf[m], p[b]);
          }
        }

        if (k0 + 63 > q0 + w*32) {
          #pragma unroll
          for (int b = 0; b < 2; b++)
            #pragma unroll
            for (int r = 0; r < 16; r++) {
              const int kg = k0 + 32*b + (r & 3) + 8*(r >> 2) + 4*hi;
              if (kg > qg) p[b][r] = -1e30f;
            }
        }

        float rloc = -1e30f;
        #pragma unroll
        for (int b = 0; b < 2; b++)
          #pragma unroll
          for (int r = 0; r < 16; r++) rloc = fmaxf(rloc, p[b][r]);
        const float rmax = xmax32(rloc);

        if (__any(rmax > m_r + 8.0f)) {
          const float mn = fmaxf(m_r, rmax);
          const float alpha = __builtin_amdgcn_exp2f(m_r - mn);
          m_r = mn;
          l_r *= alpha;
          #pragma unroll
          for (int r = 0; r < 16; r++) {
            const float ar = __shfl(alpha, (r & 3) + 8*(r >> 2) + 4*hi);
            o[0][r] *= ar; o[1][r] *= ar;
          }
        }

        float sloc = 0.f;
        #pragma unroll
        for (int b = 0; b < 2; b++)
          #pragma unroll
          for (int r = 0; r < 16; r++) {
            const float e = __builtin_amdgcn_exp2f(p[b][r] - m_r);
            p[b][r] = e;
            sloc += e;
          }
        l_r += xadd32(sloc);

        bf16x8 pa[4];
        #pragma unroll
        for (int c = 0; c < 4; c++) {
          const int b = c >> 1, R = (c & 1) * 8;
          unsigned w01 = cvtpk(p[b][R+0], p[b][R+1]);
          unsigned w23 = cvtpk(p[b][R+2], p[b][R+3]);
          unsigned w89 = cvtpk(p[b][R+4], p[b][R+5]);
          unsigned wab = cvtpk(p[b][R+6], p[b][R+7]);
          uintx2 s1 = plswap(w01, w89);
          uintx2 s2 = plswap(w23, wab);
          union { unsigned u[4]; bf16x8 v; } uu;
          uu.u[0] = s1[0]; uu.u[1] = s2[0]; uu.u[2] = s1[1]; uu.u[3] = s2[1];
          pa[c] = uu.v;
        }

        #pragma unroll
        for (int d = 0; d < 2; d++) {
          #pragma unroll
          for (int c = 0; c < 4; c++) {
            const int row = 32*d + (l & 31);
            const int cc = 2*c + hi;
            bf16x8 vf = *(const bf16x8*)((const char*)Vs[cur] + row*128 + ((cc ^ (row & 7))*16));
            o[d] = mfma32(pa[c], vf, o[d]);
          }
        }
      }

      if (kt + 2 < nt) { asm volatile("s_waitcnt vmcnt(4)" ::: "memory"); }
      else             { asm volatile("s_waitcnt vmcnt(0)" ::: "memory"); }
      __builtin_amdgcn_sched_barrier(0);
      __builtin_amdgcn_s_barrier();
      __builtin_amdgcn_sched_barrier(0);
      cur = (cur == 2) ? 0 : cur + 1;
    }

    const float inv = 1.0f / l_r;
    #pragma unroll
    for (int r = 0; r < 16; r++) {
      const int qr = (r & 3) + 8*(r >> 2) + 4*hi;
      const float ir = __shfl(inv, qr);
      const int q = q0 + w*32 + qr;
      #pragma unroll
      for (int d = 0; d < 2; d++)
        Aout[(size_t)(bb*SEQ + q)*HID + hh*HS + d*32 + (l & 31)] = (bf16)(o[d][r] * ir);
    }
  }
}

// ---------------- launch ----------------
extern "C" void kernel_launch(void* const* d_in, const int* in_sizes, int n_in,
                              void* d_out, int out_size, void* d_ws, size_t ws_size,
                              hipStream_t stream) {
  const float* x  = (const float*)d_in[0];
  const float* Wq = (const float*)d_in[1];
  const float* bq = (const float*)d_in[2];
  const float* Wk = (const float*)d_in[3];
  const float* bk = (const float*)d_in[4];
  const float* Wv = (const float*)d_in[5];
  const float* bv = (const float*)d_in[6];
  const float* Wo = (const float*)d_in[7];
  const float* bo = (const float*)d_in[8];

  char* ws = (char*)d_ws;
  const size_t MB = 1024 * 1024;
  bf16* xb  = (bf16*)(ws);
  bf16* wqb = (bf16*)(ws + 16*MB);
  bf16* wkb = (bf16*)(ws + 18*MB);
  bf16* wvb = (bf16*)(ws + 20*MB);
  bf16* wob = (bf16*)(ws + 22*MB);
  bf16* Qb  = (bf16*)(ws + 24*MB);
  bf16* Kb  = (bf16*)(ws + 40*MB);
  bf16* Vb  = (bf16*)(ws + 56*MB);
  bf16* Ab  = xb;

  k_cvt_all<<<(XN4 + 4*WN4 + 255)/256, 256, 0, stream>>>(x, Wq, Wk, Wv, Wo, xb, wqb, wkb, wvb, wob);

  k_gemm_p<0><<<dim3(MR/128, 12), 512, 0, stream>>>(xb, wqb, wkb, wvb, bq, bk, bv, Qb, Kb, Vb);

  k_attn<<<dim3(BB*NH, 8), 256, 0, stream>>>(Qb, Kb, Vb, Ab);

  k_gemm_o<<<dim3(MR/128, 8), 256, 0, stream>>>(Ab, wob, bo, (float*)d_out);
}

// Round 18
// 161.200 us; speedup vs baseline: 1.0576x; 1.0441x over previous
//
#include <hip/hip_runtime.h>

#define NH 16
#define HS 64
#define HID 1024
#define SEQ 2048
#define BB 4
#define MR (BB*SEQ)   // 8192 rows
#define KD 1024
#define NT 32         // K-tiles of 32
#define QSCALE 0.18033688f   // 0.125 * log2(e): softmax in base-2 domain

typedef __bf16 bf16;
typedef __attribute__((ext_vector_type(8))) __bf16 bf16x8;
typedef __attribute__((ext_vector_type(4))) __bf16 bf16x4;
typedef __attribute__((ext_vector_type(4))) float f32x4;
typedef __attribute__((ext_vector_type(16))) float f32x16;
typedef __attribute__((ext_vector_type(4))) float f4;
typedef __attribute__((ext_vector_type(2))) unsigned uintx2;

typedef __attribute__((address_space(3))) unsigned int as3u;
typedef __attribute__((address_space(1))) unsigned int as1u;

__device__ __forceinline__ void gl_lds16(const void* g, void* l) {
  __builtin_amdgcn_global_load_lds((const as1u*)g, (as3u*)l, 16, 0, 0);
}

__device__ __forceinline__ f32x4 mfma16(bf16x8 a, bf16x8 b, f32x4 c) {
  return __builtin_amdgcn_mfma_f32_16x16x32_bf16(a, b, c, 0, 0, 0);
}

__device__ __forceinline__ f32x16 mfma32(bf16x8 a, bf16x8 b, f32x16 c) {
  return __builtin_amdgcn_mfma_f32_32x32x16_bf16(a, b, c, 0, 0, 0);
}

__device__ __forceinline__ uintx2 plswap(unsigned a, unsigned b) {
#if __has_builtin(__builtin_amdgcn_permlane32_swap)
  return __builtin_amdgcn_permlane32_swap(a, b, false, false);
#else
  asm volatile("v_permlane32_swap_b32 %0, %1" : "+&v"(a), "+v"(b));
  uintx2 r; r[0] = a; r[1] = b; return r;
#endif
}

__device__ __forceinline__ float xmax32(float x) {
  uintx2 r = plswap(__float_as_uint(x), __float_as_uint(x));
  return fmaxf(__uint_as_float(r[0]), __uint_as_float(r[1]));
}
__device__ __forceinline__ float xadd32(float x) {
  uintx2 r = plswap(__float_as_uint(x), __float_as_uint(x));
  return __uint_as_float(r[0]) + __uint_as_float(r[1]);
}

__device__ __forceinline__ unsigned cvtpk(float lo, float hi) {
  unsigned r;
  asm("v_cvt_pk_bf16_f32 %0, %1, %2" : "=v"(r) : "v"(lo), "v"(hi));
  return r;
}

// ---------------- fp32 -> bf16: all 5 tensors in one launch ----------------
#define XN4   (MR*HID/4)
#define WN4   (HID*KD/4)
__global__ __launch_bounds__(256) void k_cvt_all(const float* __restrict__ x,
                                                 const float* __restrict__ w0, const float* __restrict__ w1,
                                                 const float* __restrict__ w2, const float* __restrict__ w3,
                                                 bf16* __restrict__ xb,
                                                 bf16* __restrict__ o0, bf16* __restrict__ o1,
                                                 bf16* __restrict__ o2, bf16* __restrict__ o3) {
  int i = blockIdx.x * 256 + threadIdx.x;
  const float* in; bf16* out; int j;
  if (i < XN4)            { in = x;  out = xb; j = i; }
  else if (i < XN4+WN4)   { in = w0; out = o0; j = i - XN4; }
  else if (i < XN4+2*WN4) { in = w1; out = o1; j = i - XN4 - WN4; }
  else if (i < XN4+3*WN4) { in = w2; out = o2; j = i - XN4 - 2*WN4; }
  else                    { in = w3; out = o3; j = i - XN4 - 3*WN4; }
  f4 v = reinterpret_cast<const f4*>(in)[j];
  bf16x4 h;
  h[0] = (bf16)v[0]; h[1] = (bf16)v[1]; h[2] = (bf16)v[2]; h[3] = (bf16)v[3];
  reinterpret_cast<bf16x4*>(out)[j] = h;
}

// ---------------- pipelined NT GEMM (R7-proven): BM=128, BN=256, BK=32, 3-buffer, counted vmcnt ----------------
// MODE 0: QKV fused — blockIdx.y: y>>2 selects {Q,K,V}, (y&3)*256 = n0.
template<int MODE>
__global__ __launch_bounds__(512, 4) void k_gemm_p(const bf16* __restrict__ A,
                                                   const bf16* __restrict__ w0, const bf16* __restrict__ w1,
                                                   const bf16* __restrict__ w2,
                                                   const float* __restrict__ b0, const float* __restrict__ b1,
                                                   const float* __restrict__ b2p,
                                                   void* __restrict__ o0, void* __restrict__ o1,
                                                   void* __restrict__ o2) {
  __shared__ __align__(16) bf16 As[3][128*32];
  __shared__ __align__(16) bf16 Bs[3][256*32];
  const int tid = threadIdx.x, l = tid & 63, w = tid >> 6;
  const int wr = w >> 2, wc = w & 3;
  const int m0 = blockIdx.x * 128;
  const int ny = blockIdx.y;
  const int which = (MODE == 0) ? (ny >> 2) : 0;
  const int n0 = (MODE == 0) ? (ny & 3) * 256 : ny * 256;
  const bf16* Bw = (MODE == 1) ? w0 : (which == 0 ? w0 : which == 1 ? w1 : w2);
  const float* bias = (MODE == 1) ? b0 : (which == 0 ? b0 : which == 1 ? b1 : b2p);

  const int sra = tid >> 2;
  const int sca = (tid & 3) ^ ((sra >> 1) & 3);
  const bf16* Ag = A  + (size_t)(m0 + sra) * KD + sca * 8;
  const bf16* Bg = Bw + (size_t)(n0 + sra) * KD + sca * 8;

  gl_lds16(Ag,                        (char*)As[0] + w * 1024);
  gl_lds16(Bg,                        (char*)Bs[0] + w * 1024);
  gl_lds16(Bg + (size_t)128 * KD,     (char*)Bs[0] + 8192 + w * 1024);
  gl_lds16(Ag + 32,                   (char*)As[1] + w * 1024);
  gl_lds16(Bg + 32,                   (char*)Bs[1] + w * 1024);
  gl_lds16(Bg + (size_t)128 * KD + 32, (char*)Bs[1] + 8192 + w * 1024);

  f32x4 acc[4][4] = {};
  const int la = l & 15, lg = l >> 4;

  for (int t = 0; t < NT; ++t) {
    const int bq = t % 3;
    if (t < NT - 1) { asm volatile("s_waitcnt vmcnt(3)" ::: "memory"); }
    else            { asm volatile("s_waitcnt vmcnt(0)" ::: "memory"); }
    __builtin_amdgcn_sched_barrier(0);
    __builtin_amdgcn_s_barrier();
    __builtin_amdgcn_sched_barrier(0);

    bf16x8 af[4], bf_[2];
    #pragma unroll
    for (int mf = 0; mf < 4; mf++) {
      const int ra = wr * 64 + mf * 16 + la;
      const int ca = lg ^ ((ra >> 1) & 3);
      af[mf] = *(const bf16x8*)((const char*)As[bq] + ra * 64 + ca * 16);
    }
    #pragma unroll
    for (int nf = 0; nf < 2; nf++) {
      const int rb = wc * 64 + nf * 16 + la;
      const int cb = lg ^ ((rb >> 1) & 3);
      bf_[nf] = *(const bf16x8*)((const char*)Bs[bq] + rb * 64 + cb * 16);
    }
    const int t2 = t + 2;
    if (t2 < NT) {
      const int b2 = t2 % 3;
      gl_lds16(Ag + t2 * 32, (char*)As[b2] + w * 1024);
      gl_lds16(Bg + t2 * 32, (char*)Bs[b2] + w * 1024);
    }
    asm volatile("s_waitcnt lgkmcnt(0)" ::: "memory");
    __builtin_amdgcn_sched_barrier(0);
    __builtin_amdgcn_s_setprio(1);
    #pragma unroll
    for (int mf = 0; mf < 4; mf++) {
      acc[mf][0] = mfma16(af[mf], bf_[0], acc[mf][0]);
      acc[mf][1] = mfma16(af[mf], bf_[1], acc[mf][1]);
    }
    __builtin_amdgcn_s_setprio(0);

    #pragma unroll
    for (int nf = 0; nf < 2; nf++) {
      const int rb = wc * 64 + (nf + 2) * 16 + la;
      const int cb = lg ^ ((rb >> 1) & 3);
      bf_[nf] = *(const bf16x8*)((const char*)Bs[bq] + rb * 64 + cb * 16);
    }
    if (t2 < NT) {
      const int b2 = t2 % 3;
      gl_lds16(Bg + (size_t)128 * KD + t2 * 32, (char*)Bs[b2] + 8192 + w * 1024);
    }
    asm volatile("s_waitcnt lgkmcnt(0)" ::: "memory");
    __builtin_amdgcn_sched_barrier(0);
    __builtin_amdgcn_s_setprio(1);
    #pragma unroll
    for (int mf = 0; mf < 4; mf++) {
      acc[mf][2] = mfma16(af[mf], bf_[0], acc[mf][2]);
      acc[mf][3] = mfma16(af[mf], bf_[1], acc[mf][3]);
    }
    __builtin_amdgcn_s_setprio(0);
  }

  const float scale = (MODE == 0 && which == 0) ? QSCALE : 1.0f;
  #pragma unroll
  for (int mf = 0; mf < 4; mf++) {
    #pragma unroll
    for (int nf = 0; nf < 4; nf++) {
      const int n = n0 + wc * 64 + nf * 16 + la;
      const float bn = bias[n];
      #pragma unroll
      for (int j = 0; j < 4; j++) {
        const int m = m0 + wr * 64 + mf * 16 + lg * 4 + j;
        const float v = (acc[mf][nf][j] + bn) * scale;
        if (MODE == 0) {
          if (which == 2) {
            ((bf16*)o2)[(((size_t)(m >> 11) * NH + (n >> 6)) * HS + (n & 63)) * SEQ + (m & (SEQ - 1))] = (bf16)v;
          } else {
            bf16* dst = (which == 0) ? (bf16*)o0 : (bf16*)o1;
            dst[(((size_t)(m >> 11) * NH + (n >> 6)) * SEQ + (m & (SEQ - 1))) * HS + (n & 63)] = (bf16)v;
          }
        } else {
          ((float*)o0)[(size_t)m * HID + n] = v;
        }
      }
    }
  }
}

// ---------------- o-proj GEMM: BM=128, BN=128, 256 thr, 3-buf, 48KB -> 3/CU, 512 blocks ----------------
__global__ __launch_bounds__(256, 3) void k_gemm_o(const bf16* __restrict__ A,
                                                   const bf16* __restrict__ Bw,
                                                   const float* __restrict__ bias,
                                                   float* __restrict__ outp) {
  __shared__ __align__(16) bf16 As[3][128*32];
  __shared__ __align__(16) bf16 Bs[3][128*32];
  const int tid = threadIdx.x, l = tid & 63, w = tid >> 6;
  const int wr = w >> 1, wc = w & 1;
  const int m0 = blockIdx.x * 128;
  const int n0 = blockIdx.y * 128;

  const int sra = tid >> 2;
  const int sca = (tid & 3) ^ ((sra >> 1) & 3);
  const bf16* Ag = A  + (size_t)(m0 + sra) * KD + sca * 8;
  const bf16* Bg = Bw + (size_t)(n0 + sra) * KD + sca * 8;

  gl_lds16(Ag,                        (char*)As[0] + w * 1024);
  gl_lds16(Ag + (size_t)64 * KD,      (char*)As[0] + 4096 + w * 1024);
  gl_lds16(Bg,                        (char*)Bs[0] + w * 1024);
  gl_lds16(Bg + (size_t)64 * KD,      (char*)Bs[0] + 4096 + w * 1024);
  gl_lds16(Ag + 32,                   (char*)As[1] + w * 1024);
  gl_lds16(Ag + (size_t)64 * KD + 32, (char*)As[1] + 4096 + w * 1024);
  gl_lds16(Bg + 32,                   (char*)Bs[1] + w * 1024);
  gl_lds16(Bg + (size_t)64 * KD + 32, (char*)Bs[1] + 4096 + w * 1024);

  f32x4 acc[4][4] = {};
  const int la = l & 15, lg = l >> 4;

  for (int t = 0; t < NT; ++t) {
    const int bq = t % 3;
    if (t < NT - 1) { asm volatile("s_waitcnt vmcnt(4)" ::: "memory"); }
    else            { asm volatile("s_waitcnt vmcnt(0)" ::: "memory"); }
    __builtin_amdgcn_sched_barrier(0);
    __builtin_amdgcn_s_barrier();
    __builtin_amdgcn_sched_barrier(0);

    bf16x8 af[4], bf_[2];
    #pragma unroll
    for (int mf = 0; mf < 4; mf++) {
      const int ra = wr * 64 + mf * 16 + la;
      const int ca = lg ^ ((ra >> 1) & 3);
      af[mf] = *(const bf16x8*)((const char*)As[bq] + ra * 64 + ca * 16);
    }
    #pragma unroll
    for (int nf = 0; nf < 2; nf++) {
      const int rb = wc * 64 + nf * 16 + la;
      const int cb = lg ^ ((rb >> 1) & 3);
      bf_[nf] = *(const bf16x8*)((const char*)Bs[bq] + rb * 64 + cb * 16);
    }
    const int t2 = t + 2;
    if (t2 < NT) {
      const int b2 = t2 % 3;
      gl_lds16(Ag + t2 * 32,                   (char*)As[b2] + w * 1024);
      gl_lds16(Ag + (size_t)64 * KD + t2 * 32, (char*)As[b2] + 4096 + w * 1024);
    }
    asm volatile("s_waitcnt lgkmcnt(0)" ::: "memory");
    __builtin_amdgcn_sched_barrier(0);
    __builtin_amdgcn_s_setprio(1);
    #pragma unroll
    for (int mf = 0; mf < 4; mf++) {
      acc[mf][0] = mfma16(af[mf], bf_[0], acc[mf][0]);
      acc[mf][1] = mfma16(af[mf], bf_[1], acc[mf][1]);
    }
    __builtin_amdgcn_s_setprio(0);

    #pragma unroll
    for (int nf = 0; nf < 2; nf++) {
      const int rb = wc * 64 + (nf + 2) * 16 + la;
      const int cb = lg ^ ((rb >> 1) & 3);
      bf_[nf] = *(const bf16x8*)((const char*)Bs[bq] + rb * 64 + cb * 16);
    }
    if (t2 < NT) {
      const int b2 = t2 % 3;
      gl_lds16(Bg + t2 * 32,                   (char*)Bs[b2] + w * 1024);
      gl_lds16(Bg + (size_t)64 * KD + t2 * 32, (char*)Bs[b2] + 4096 + w * 1024);
    }
    asm volatile("s_waitcnt lgkmcnt(0)" ::: "memory");
    __builtin_amdgcn_sched_barrier(0);
    __builtin_amdgcn_s_setprio(1);
    #pragma unroll
    for (int mf = 0; mf < 4; mf++) {
      acc[mf][2] = mfma16(af[mf], bf_[0], acc[mf][2]);
      acc[mf][3] = mfma16(af[mf], bf_[1], acc[mf][3]);
    }
    __builtin_amdgcn_s_setprio(0);
  }

  #pragma unroll
  for (int mf = 0; mf < 4; mf++) {
    #pragma unroll
    for (int nf = 0; nf < 4; nf++) {
      const int n = n0 + wc * 64 + nf * 16 + la;
      const float bn = bias[n];
      #pragma unroll
      for (int j = 0; j < 4; j++) {
        const int m = m0 + wr * 64 + mf * 16 + lg * 4 + j;
        outp[(size_t)m * HID + n] = acc[mf][nf][j] + bn;
      }
    }
  }
}

// ---------------- causal flash attention: one q-tile per block, LPT order, 3 blocks/CU ----------------
// grid(64, 16): bh = blockIdx.x (XCD head grouping); p = 15 - blockIdx.y so the
// longest blocks (p=15, 32 kv-tiles) dispatch first and short ones backfill the tail.
__global__ __launch_bounds__(256, 3) void k_attn(const bf16* __restrict__ Q,
                                                 const bf16* __restrict__ K,
                                                 const bf16* __restrict__ Vt,
                                                 bf16* __restrict__ Aout) {
  const int bh = blockIdx.x;
  const int tid = threadIdx.x, l = tid & 63, w = tid >> 6;
  const int hi = l >> 5;

  __shared__ __align__(16) bf16 Ks[3][64*64];
  __shared__ __align__(16) bf16 Vs[3][64*64];

  const bf16* Qg = Q  + (size_t)bh * SEQ * HS;
  const bf16* Kg = K  + (size_t)bh * SEQ * HS;
  const bf16* Vg = Vt + (size_t)bh * HS * SEQ;   // [d][s]

  const int bb = bh >> 4, hh = bh & 15;
  const int sr  = tid >> 3;
  const int swz = ((tid & 7) ^ (sr & 7)) * 8;

  const int p_ = 15 - blockIdx.y;   // LPT: big tiles first
  const int q0 = p_ * 128;
  const int nt = 2 * p_ + 2;

  bf16x8 qf[4];
  {
    const bf16* qrow = Qg + (size_t)(q0 + w*32 + (l & 31)) * HS + hi * 8;
    #pragma unroll
    for (int m = 0; m < 4; m++)
      qf[m] = *(const bf16x8*)(qrow + m * 16);
  }
  __builtin_amdgcn_sched_barrier(0);

  #pragma unroll
  for (int i = 0; i < 2; i++) {
    gl_lds16(Kg + (size_t)(32*i + sr) * HS + swz,  (char*)Ks[0] + i*4096 + w*1024);
    gl_lds16(Vg + (size_t)(32*i + sr) * SEQ + swz, (char*)Vs[0] + i*4096 + w*1024);
  }
  #pragma unroll
  for (int i = 0; i < 2; i++) {
    gl_lds16(Kg + (size_t)(64 + 32*i + sr) * HS + swz,  (char*)Ks[1] + i*4096 + w*1024);
    gl_lds16(Vg + (size_t)(32*i + sr) * SEQ + 64 + swz, (char*)Vs[1] + i*4096 + w*1024);
  }
  asm volatile("s_waitcnt vmcnt(4)" ::: "memory");
  __builtin_amdgcn_sched_barrier(0);
  __builtin_amdgcn_s_barrier();
  __builtin_amdgcn_sched_barrier(0);

  float m_r = -1e30f, l_r = 0.f;
  f32x16 o[2] = {};
  const int qmax = q0 + w*32 + 31;
  const int qg   = q0 + w*32 + (l & 31);

  int cur = 0;
  for (int kt = 0; kt < nt; ++kt) {
    const int k0 = kt * 64;

    if (kt + 2 < nt) {
      const int k2 = k0 + 128;
      const int b2 = (cur == 0) ? 2 : cur - 1;
      #pragma unroll
      for (int i = 0; i < 2; i++) {
        gl_lds16(Kg + (size_t)(k2 + 32*i + sr) * HS + swz,  (char*)Ks[b2] + i*4096 + w*1024);
        gl_lds16(Vg + (size_t)(32*i + sr) * SEQ + k2 + swz, (char*)Vs[b2] + i*4096 + w*1024);
      }
    }

    if (k0 <= qmax) {
      f32x16 p[2] = {};
      #pragma unroll
      for (int b = 0; b < 2; b++) {
        #pragma unroll
        for (int m = 0; m < 4; m++) {
          const int row = 32*b + (l & 31);
          const int cc = 2*m + hi;
          bf16x8 kf = *(const bf16x8*)((const char*)Ks[cur] + row*128 + ((cc ^ (row & 7))*16));
          p[b] = mfma32(kf, qf[m], p[b]);
        }
      }

      if (k0 + 63 > q0 + w*32) {
        #pragma unroll
        for (int b = 0; b < 2; b++)
          #pragma unroll
          for (int r = 0; r < 16; r++) {
            const int kg = k0 + 32*b + (r & 3) + 8*(r >> 2) + 4*hi;
            if (kg > qg) p[b][r] = -1e30f;
          }
      }

      float rloc = -1e30f;
      #pragma unroll
      for (int b = 0; b < 2; b++)
        #pragma unroll
        for (int r = 0; r < 16; r++) rloc = fmaxf(rloc, p[b][r]);
      const float rmax = xmax32(rloc);

      if (__any(rmax > m_r + 8.0f)) {
        const float mn = fmaxf(m_r, rmax);
        const float alpha = __builtin_amdgcn_exp2f(m_r - mn);
        m_r = mn;
        l_r *= alpha;
        #pragma unroll
        for (int r = 0; r < 16; r++) {
          const float ar = __shfl(alpha, (r & 3) + 8*(r >> 2) + 4*hi);
          o[0][r] *= ar; o[1][r] *= ar;
        }
      }

      float sloc = 0.f;
      #pragma unroll
      for (int b = 0; b < 2; b++)
        #pragma unroll
        for (int r = 0; r < 16; r++) {
          const float e = __builtin_amdgcn_exp2f(p[b][r] - m_r);
          p[b][r] = e;
          sloc += e;
        }
      l_r += xadd32(sloc);

      bf16x8 pa[4];
      #pragma unroll
      for (int c = 0; c < 4; c++) {
        const int b = c >> 1, R = (c & 1) * 8;
        unsigned w01 = cvtpk(p[b][R+0], p[b][R+1]);
        unsigned w23 = cvtpk(p[b][R+2], p[b][R+3]);
        unsigned w89 = cvtpk(p[b][R+4], p[b][R+5]);
        unsigned wab = cvtpk(p[b][R+6], p[b][R+7]);
        uintx2 s1 = plswap(w01, w89);
        uintx2 s2 = plswap(w23, wab);
        union { unsigned u[4]; bf16x8 v; } uu;
        uu.u[0] = s1[0]; uu.u[1] = s2[0]; uu.u[2] = s1[1]; uu.u[3] = s2[1];
        pa[c] = uu.v;
      }

      #pragma unroll
      for (int d = 0; d < 2; d++) {
        #pragma unroll
        for (int c = 0; c < 4; c++) {
          const int row = 32*d + (l & 31);
          const int cc = 2*c + hi;
          bf16x8 vf = *(const bf16x8*)((const char*)Vs[cur] + row*128 + ((cc ^ (row & 7))*16));
          o[d] = mfma32(pa[c], vf, o[d]);
        }
      }
    }

    if (kt + 2 < nt) { asm volatile("s_waitcnt vmcnt(4)" ::: "memory"); }
    else             { asm volatile("s_waitcnt vmcnt(0)" ::: "memory"); }
    __builtin_amdgcn_sched_barrier(0);
    __builtin_amdgcn_s_barrier();
    __builtin_amdgcn_sched_barrier(0);
    cur = (cur == 2) ? 0 : cur + 1;
  }

  const float inv = 1.0f / l_r;
  #pragma unroll
  for (int r = 0; r < 16; r++) {
    const int qr = (r & 3) + 8*(r >> 2) + 4*hi;
    const float ir = __shfl(inv, qr);
    const int q = q0 + w*32 + qr;
    #pragma unroll
    for (int d = 0; d < 2; d++)
      Aout[(size_t)(bb*SEQ + q)*HID + hh*HS + d*32 + (l & 31)] = (bf16)(o[d][r] * ir);
  }
}

// ---------------- launch ----------------
extern "C" void kernel_launch(void* const* d_in, const int* in_sizes, int n_in,
                              void* d_out, int out_size, void* d_ws, size_t ws_size,
                              hipStream_t stream) {
  const float* x  = (const float*)d_in[0];
  const float* Wq = (const float*)d_in[1];
  const float* bq = (const float*)d_in[2];
  const float* Wk = (const float*)d_in[3];
  const float* bk = (const float*)d_in[4];
  const float* Wv = (const float*)d_in[5];
  const float* bv = (const float*)d_in[6];
  const float* Wo = (const float*)d_in[7];
  const float* bo = (const float*)d_in[8];

  char* ws = (char*)d_ws;
  const size_t MB = 1024 * 1024;
  bf16* xb  = (bf16*)(ws);
  bf16* wqb = (bf16*)(ws + 16*MB);
  bf16* wkb = (bf16*)(ws + 18*MB);
  bf16* wvb = (bf16*)(ws + 20*MB);
  bf16* wob = (bf16*)(ws + 22*MB);
  bf16* Qb  = (bf16*)(ws + 24*MB);
  bf16* Kb  = (bf16*)(ws + 40*MB);
  bf16* Vb  = (bf16*)(ws + 56*MB);
  bf16* Ab  = xb;

  k_cvt_all<<<(XN4 + 4*WN4 + 255)/256, 256, 0, stream>>>(x, Wq, Wk, Wv, Wo, xb, wqb, wkb, wvb, wob);

  k_gemm_p<0><<<dim3(MR/128, 12), 512, 0, stream>>>(xb, wqb, wkb, wvb, bq, bk, bv, Qb, Kb, Vb);

  k_attn<<<dim3(BB*NH, 16), 256, 0, stream>>>(Qb, Kb, Vb, Ab);

  k_gemm_o<<<dim3(MR/128, 8), 256, 0, stream>>>(Ab, wob, bo, (float*)d_out);
}